// Round 1
// baseline (236.246 us; speedup 1.0000x reference)
//
#include <hip/hip_runtime.h>
#include <stdint.h>

// MultiHeadAttention fused pipeline for MI355X (gfx950).
// B=2, T=2048, C=1024, H=16, Dh=64. All inputs fp32; compute in bf16 MFMA.
//
// ws layout (48 MiB):
//   [ 0MB) xb   : x as bf16            [4096][1024]
//   [ 8MB) Wqt  : Wq^T bf16            [1024 n][1024 k]
//   [10MB) Wkt, [12MB) Wvt, [14MB) Wpt
//   [16MB) Qb   : [32 head][2048 t][64 d] bf16
//   [24MB) Kb   : same layout
//   [32MB) Vb   : TRANSPOSED [32 head][64 d][2048 t] bf16
//   [40MB) Ab   : attention out [4096 row=b*T+t][1024 col=h*64+d] bf16

typedef unsigned short bfu;                               // bf16 bits
typedef short bf16x8 __attribute__((ext_vector_type(8))); // 8 bf16 (4 VGPRs)
typedef float f32x4 __attribute__((ext_vector_type(4)));

#define DEVI static __device__ __forceinline__

DEVI bfu f2bf(float f) {  // round-to-nearest-even fp32 -> bf16 bits
  union { float f; unsigned u; } a; a.f = f;
  unsigned u = a.u;
  u += 0x7fffu + ((u >> 16) & 1u);
  return (bfu)(u >> 16);
}

DEVI void gld_lds16(const void* g, void* l) {
  __builtin_amdgcn_global_load_lds(
      (const __attribute__((address_space(1))) void*)g,
      (__attribute__((address_space(3))) void*)l, 16, 0, 0);
}

// ---------------- prep kernels ----------------

__global__ __launch_bounds__(256) void conv_x(const float* __restrict__ x,
                                              bfu* __restrict__ xb) {
  const int n4 = (4096 * 1024) / 4;
  for (int i = blockIdx.x * 256 + threadIdx.x; i < n4; i += gridDim.x * 256) {
    float4 v = ((const float4*)x)[i];
    ushort4 p;
    p.x = f2bf(v.x); p.y = f2bf(v.y); p.z = f2bf(v.z); p.w = f2bf(v.w);
    ((ushort4*)xb)[i] = p;
  }
}

// convert + transpose a 1024x1024 fp32 [k][n] -> bf16 [n][k]
__global__ __launch_bounds__(256) void conv_w(
    const float* __restrict__ W0, const float* __restrict__ W1,
    const float* __restrict__ W2, const float* __restrict__ W3,
    bfu* __restrict__ T0, bfu* __restrict__ T1,
    bfu* __restrict__ T2, bfu* __restrict__ T3) {
  __shared__ bfu tile[64][65];
  const float* W; bfu* T;
  switch (blockIdx.z) {
    case 0:  W = W0; T = T0; break;
    case 1:  W = W1; T = T1; break;
    case 2:  W = W2; T = T2; break;
    default: W = W3; T = T3; break;
  }
  const int k0 = blockIdx.y * 64, n0 = blockIdx.x * 64;
  const int c = threadIdx.x & 63, r4 = threadIdx.x >> 6;
#pragma unroll
  for (int i = 0; i < 16; i++) {
    int row = r4 + i * 4;  // k-local
    tile[row][c] = f2bf(W[(size_t)(k0 + row) * 1024 + n0 + c]);
  }
  __syncthreads();
#pragma unroll
  for (int i = 0; i < 16; i++) {
    int row = r4 + i * 4;  // n-local
    T[(size_t)(n0 + row) * 1024 + k0 + c] = tile[c][row];
  }
}

// ---------------- GEMM core (m97 structure: 128x128 tile, BK=32) ----------------
// C[M,N] = A[M,K] * Bt[N,K]^T, A/Bt bf16 row-major. 256 threads = 4 waves (2x2).

DEVI void gemm128_core(const bfu* __restrict__ A, const bfu* __restrict__ Bt,
                       int K, int m0, int n0, bfu* As, bfu* Bs, int tid,
                       f32x4 acc[4][4]) {
  const int lane = tid & 63, wave = tid >> 6;
  const int wr = wave >> 1, wc = wave & 1;
  const int fr = lane & 15, fq = lane >> 4;
  const int r_a = tid >> 2;          // 0..63 staging row
  const int koff = (tid & 3) * 8;    // staging k offset (bf16 units)
  for (int k0 = 0; k0 < K; k0 += 32) {
    __syncthreads();
    gld_lds16(A  + (size_t)(m0 +      r_a) * K + k0 + koff, As        + tid * 8);
    gld_lds16(A  + (size_t)(m0 + 64 + r_a) * K + k0 + koff, As + 2048 + tid * 8);
    gld_lds16(Bt + (size_t)(n0 +      r_a) * K + k0 + koff, Bs        + tid * 8);
    gld_lds16(Bt + (size_t)(n0 + 64 + r_a) * K + k0 + koff, Bs + 2048 + tid * 8);
    __syncthreads();
    bf16x8 af[4], bfv[4];
#pragma unroll
    for (int m = 0; m < 4; m++)
      af[m] = *(const bf16x8*)&As[(wr * 64 + m * 16 + fr) * 32 + fq * 8];
#pragma unroll
    for (int n = 0; n < 4; n++)
      bfv[n] = *(const bf16x8*)&Bs[(wc * 64 + n * 16 + fr) * 32 + fq * 8];
#pragma unroll
    for (int m = 0; m < 4; m++)
#pragma unroll
      for (int n = 0; n < 4; n++)
        acc[m][n] = __builtin_amdgcn_mfma_f32_16x16x32_bf16(af[m], bfv[n],
                                                            acc[m][n], 0, 0, 0);
  }
}

// QKV projection: z=0 -> Q, z=1 -> K (layout [h32][t2048][d64]),
//                 z=2 -> V transposed ([h32][d64][t2048])
__global__ __launch_bounds__(256) void gemm_qkv(
    const bfu* __restrict__ A, const bfu* __restrict__ Wqt,
    const bfu* __restrict__ Wkt, const bfu* __restrict__ Wvt,
    bfu* __restrict__ Qb, bfu* __restrict__ Kb, bfu* __restrict__ Vb) {
  __shared__ __align__(16) bfu As[128 * 32];
  __shared__ __align__(16) bfu Bs[128 * 32];
  const bfu* Bt; bfu* out; int epi;
  if (blockIdx.z == 0)      { Bt = Wqt; out = Qb; epi = 0; }
  else if (blockIdx.z == 1) { Bt = Wkt; out = Kb; epi = 0; }
  else                      { Bt = Wvt; out = Vb; epi = 1; }
  const int m0 = blockIdx.y * 128, n0 = blockIdx.x * 128;
  const int tid = threadIdx.x, lane = tid & 63, wave = tid >> 6;
  const int wr = wave >> 1, wc = wave & 1, fr = lane & 15, fq = lane >> 4;
  f32x4 acc[4][4] = {};
  gemm128_core(A, Bt, 1024, m0, n0, As, Bs, tid, acc);
#pragma unroll
  for (int m = 0; m < 4; m++)
#pragma unroll
    for (int n = 0; n < 4; n++) {
      int r = m0 + wr * 64 + m * 16 + fq * 4;  // global row (b*2048+t), +i
      int c = n0 + wc * 64 + n * 16 + fr;      // global col (h*64+d)
      int b = r >> 11, t = r & 2047, h = c >> 6, d = c & 63;
      if (epi == 0) {
        size_t base = ((size_t)(b * 16 + h) * 2048 + t) * 64 + d;
#pragma unroll
        for (int i = 0; i < 4; i++) out[base + (size_t)i * 64] = f2bf(acc[m][n][i]);
      } else {
        size_t base = ((size_t)(b * 16 + h) * 64 + d) * 2048 + t;
        ushort4 p;
        p.x = f2bf(acc[m][n][0]); p.y = f2bf(acc[m][n][1]);
        p.z = f2bf(acc[m][n][2]); p.w = f2bf(acc[m][n][3]);
        *(ushort4*)&out[base] = p;  // 4 consecutive t -> contiguous
      }
    }
}

// output projection: out[4096][1024] fp32 = Ab @ Wpt^T + bias
__global__ __launch_bounds__(256) void gemm_proj(
    const bfu* __restrict__ A, const bfu* __restrict__ Bt,
    const float* __restrict__ bias, float* __restrict__ out) {
  __shared__ __align__(16) bfu As[128 * 32];
  __shared__ __align__(16) bfu Bs[128 * 32];
  const int m0 = blockIdx.y * 128, n0 = blockIdx.x * 128;
  const int tid = threadIdx.x, lane = tid & 63, wave = tid >> 6;
  const int wr = wave >> 1, wc = wave & 1, fr = lane & 15, fq = lane >> 4;
  f32x4 acc[4][4] = {};
  gemm128_core(A, Bt, 1024, m0, n0, As, Bs, tid, acc);
#pragma unroll
  for (int m = 0; m < 4; m++)
#pragma unroll
    for (int n = 0; n < 4; n++) {
      int r = m0 + wr * 64 + m * 16 + fq * 4;
      int c = n0 + wc * 64 + n * 16 + fr;
      float bv = bias[c];
#pragma unroll
      for (int i = 0; i < 4; i++)
        out[(size_t)(r + i) * 1024 + c] = acc[m][n][i] + bv;
    }
}

// ---------------- flash attention (causal) ----------------
// grid 512: xcd-swizzled so each head-instance's K/V stays on one XCD's L2.
// 4 waves x 16 q-rows (QBLK=64), KBLK=64, paired q-blocks (qb, 31-qb) -> 33 iters/WG.

__global__ __launch_bounds__(256) void attn_fwd(
    const bfu* __restrict__ Q, const bfu* __restrict__ K,
    const bfu* __restrict__ Vt, bfu* __restrict__ Ob) {
  __shared__ __align__(16) bfu plds[4][16][72];  // per-wave P tile, +8 pad
  const int bid = blockIdx.x;
  const int xcd = bid & 7, wi = bid >> 3;
  const int hb = xcd * 4 + (wi & 3);   // head instance 0..31 (= b*16+h)
  const int pair = wi >> 2;            // 0..15
  const int tid = threadIdx.x, wave = tid >> 6, lane = tid & 63;
  const int fr = lane & 15, fq = lane >> 4;
  const bfu* Qh = Q  + (size_t)hb * 2048 * 64;
  const bfu* Kh = K  + (size_t)hb * 2048 * 64;
  const bfu* Vh = Vt + (size_t)hb * 64 * 2048;
  const int b = hb >> 4, h = hb & 15;
  for (int rep = 0; rep < 2; rep++) {
    const int qb = rep ? (31 - pair) : pair;
    const int q0 = qb * 64;
    const int qrow = q0 + wave * 16;   // this wave's 16 q rows
    bf16x8 qf[2];
    qf[0] = *(const bf16x8*)&Qh[(size_t)(qrow + fr) * 64 + fq * 8];
    qf[1] = *(const bf16x8*)&Qh[(size_t)(qrow + fr) * 64 + 32 + fq * 8];
    float mrow[4], lrow[4];
    f32x4 o[4] = {};
#pragma unroll
    for (int i = 0; i < 4; i++) { mrow[i] = -1e30f; lrow[i] = 0.f; }
    for (int kb = 0; kb <= qb; kb++) {
      const int kbase = kb * 64;
      // S = Q K^T  (rows = q (fq*4+i), cols = k (fr))
      f32x4 s[4] = {};
#pragma unroll
      for (int kt = 0; kt < 4; kt++)
#pragma unroll
        for (int kk = 0; kk < 2; kk++) {
          bf16x8 kf = *(const bf16x8*)&Kh[(size_t)(kbase + kt * 16 + fr) * 64 +
                                          kk * 32 + fq * 8];
          s[kt] = __builtin_amdgcn_mfma_f32_16x16x32_bf16(qf[kk], kf, s[kt], 0, 0, 0);
        }
      const float sc = 0.125f;  // Dh^-0.5
      if (kb == qb) {           // diagonal block: scale + causal mask
#pragma unroll
        for (int kt = 0; kt < 4; kt++)
#pragma unroll
          for (int i = 0; i < 4; i++) {
            int tc = kbase + kt * 16 + fr;
            int tq = qrow + fq * 4 + i;
            s[kt][i] = (tc <= tq) ? s[kt][i] * sc : -1e30f;
          }
      } else {
#pragma unroll
        for (int kt = 0; kt < 4; kt++) s[kt] *= sc;
      }
      // online softmax, wave-parallel (reduce over 16 lanes holding the cols)
      float mnew[4], al[4], rs[4];
#pragma unroll
      for (int i = 0; i < 4; i++) {
        float v = fmaxf(fmaxf(s[0][i], s[1][i]), fmaxf(s[2][i], s[3][i]));
        v = fmaxf(v, __shfl_xor(v, 1));
        v = fmaxf(v, __shfl_xor(v, 2));
        v = fmaxf(v, __shfl_xor(v, 4));
        v = fmaxf(v, __shfl_xor(v, 8));
        mnew[i] = fmaxf(mrow[i], v);
        rs[i] = 0.f;
      }
#pragma unroll
      for (int kt = 0; kt < 4; kt++)
#pragma unroll
        for (int i = 0; i < 4; i++) {
          float p = __expf(s[kt][i] - mnew[i]);
          s[kt][i] = p;
          rs[i] += p;
        }
#pragma unroll
      for (int i = 0; i < 4; i++) {
        rs[i] += __shfl_xor(rs[i], 1);
        rs[i] += __shfl_xor(rs[i], 2);
        rs[i] += __shfl_xor(rs[i], 4);
        rs[i] += __shfl_xor(rs[i], 8);
        al[i] = __expf(mrow[i] - mnew[i]);
        lrow[i] = lrow[i] * al[i] + rs[i];
        mrow[i] = mnew[i];
      }
#pragma unroll
      for (int dt = 0; dt < 4; dt++) {
        o[dt][0] *= al[0]; o[dt][1] *= al[1];
        o[dt][2] *= al[2]; o[dt][3] *= al[3];
      }
      // P (acc layout) -> LDS -> A-fragment layout
#pragma unroll
      for (int kt = 0; kt < 4; kt++)
#pragma unroll
        for (int i = 0; i < 4; i++)
          plds[wave][fq * 4 + i][kt * 16 + fr] = f2bf(s[kt][i]);
      bf16x8 pa0 = *(const bf16x8*)&plds[wave][fr][fq * 8];
      bf16x8 pa1 = *(const bf16x8*)&plds[wave][fr][32 + fq * 8];
      // O += P V   (V read as B-frag from transposed-V global, 16B/lane)
#pragma unroll
      for (int dt = 0; dt < 4; dt++) {
        bf16x8 vf0 = *(const bf16x8*)&Vh[(size_t)(dt * 16 + fr) * 2048 + kbase + fq * 8];
        o[dt] = __builtin_amdgcn_mfma_f32_16x16x32_bf16(pa0, vf0, o[dt], 0, 0, 0);
        bf16x8 vf1 = *(const bf16x8*)&Vh[(size_t)(dt * 16 + fr) * 2048 + kbase + 32 + fq * 8];
        o[dt] = __builtin_amdgcn_mfma_f32_16x16x32_bf16(pa1, vf1, o[dt], 0, 0, 0);
      }
    }
    // epilogue: Ob[b*2048+t][h*64+d]
#pragma unroll
    for (int dt = 0; dt < 4; dt++)
#pragma unroll
      for (int i = 0; i < 4; i++) {
        int t = qrow + fq * 4 + i;
        float val = o[dt][i] / lrow[i];
        Ob[(size_t)(b * 2048 + t) * 1024 + h * 64 + dt * 16 + fr] = f2bf(val);
      }
  }
}

// ---------------- launch ----------------

extern "C" void kernel_launch(void* const* d_in, const int* in_sizes, int n_in,
                              void* d_out, int out_size, void* d_ws, size_t ws_size,
                              hipStream_t stream) {
  const float* x  = (const float*)d_in[0];
  const float* Wk = (const float*)d_in[1];  // note dict order: Wk before Wq!
  const float* Wq = (const float*)d_in[2];
  const float* Wv = (const float*)d_in[3];
  const float* Wp = (const float*)d_in[4];
  const float* bp = (const float*)d_in[5];
  char* ws = (char*)d_ws;
  bfu* xb  = (bfu*)(ws);
  bfu* Wqt = (bfu*)(ws + ( 8u << 20));
  bfu* Wkt = (bfu*)(ws + (10u << 20));
  bfu* Wvt = (bfu*)(ws + (12u << 20));
  bfu* Wpt = (bfu*)(ws + (14u << 20));
  bfu* Qb  = (bfu*)(ws + (16u << 20));
  bfu* Kb  = (bfu*)(ws + (24u << 20));
  bfu* Vb  = (bfu*)(ws + (32u << 20));
  bfu* Ab  = (bfu*)(ws + (40u << 20));
  float* out = (float*)d_out;

  conv_x<<<1024, 256, 0, stream>>>(x, xb);
  conv_w<<<dim3(16, 16, 4), 256, 0, stream>>>(Wq, Wk, Wv, Wp, Wqt, Wkt, Wvt, Wpt);
  gemm_qkv<<<dim3(8, 32, 3), 256, 0, stream>>>(xb, Wqt, Wkt, Wvt, Qb, Kb, Vb);
  attn_fwd<<<512, 256, 0, stream>>>(Qb, Kb, Vb, Ab);
  gemm_proj<<<dim3(8, 32), 256, 0, stream>>>(Ab, Wpt, bp, out);
}

// Round 2
// 151.378 us; speedup vs baseline: 1.5606x; 1.5606x over previous
//
#include <hip/hip_runtime.h>
#include <stdint.h>

// MultiHeadAttention fused pipeline for MI355X (gfx950).
// B=2, T=2048, C=1024, H=16, Dh=64. All inputs fp32; compute in bf16 MFMA.
//
// ws layout (48 MiB):
//   [ 0MB) xb   : x as bf16            [4096][1024]
//   [ 8MB) Wqt  : Wq^T bf16            [1024 n][1024 k]
//   [10MB) Wkt, [12MB) Wvt, [14MB) Wpt
//   [16MB) Qb   : [32 head][2048 t][64 d] bf16
//   [24MB) Kb   : same layout
//   [32MB) Vb   : TRANSPOSED [32 head][64 d][2048 t] bf16
//   [40MB) Ab   : attention out [4096 row=b*T+t][1024 col=h*64+d] bf16

typedef unsigned short bfu;                               // bf16 bits
typedef short bf16x8 __attribute__((ext_vector_type(8))); // 8 bf16 (4 VGPRs)
typedef float f32x4 __attribute__((ext_vector_type(4)));

#define DEVI static __device__ __forceinline__

DEVI bfu f2bf(float f) {  // round-to-nearest-even fp32 -> bf16 bits
  union { float f; unsigned u; } a; a.f = f;
  unsigned u = a.u;
  u += 0x7fffu + ((u >> 16) & 1u);
  return (bfu)(u >> 16);
}

DEVI void gld_lds16(const void* g, void* l) {
  __builtin_amdgcn_global_load_lds(
      (const __attribute__((address_space(1))) void*)g,
      (__attribute__((address_space(3))) void*)l, 16, 0, 0);
}

// ---------------- prep kernels ----------------

__global__ __launch_bounds__(256) void conv_x(const float* __restrict__ x,
                                              bfu* __restrict__ xb) {
  const int n4 = (4096 * 1024) / 4;
  for (int i = blockIdx.x * 256 + threadIdx.x; i < n4; i += gridDim.x * 256) {
    float4 v = ((const float4*)x)[i];
    ushort4 p;
    p.x = f2bf(v.x); p.y = f2bf(v.y); p.z = f2bf(v.z); p.w = f2bf(v.w);
    ((ushort4*)xb)[i] = p;
  }
}

// convert + transpose a 1024x1024 fp32 [k][n] -> bf16 [n][k]
__global__ __launch_bounds__(256) void conv_w(
    const float* __restrict__ W0, const float* __restrict__ W1,
    const float* __restrict__ W2, const float* __restrict__ W3,
    bfu* __restrict__ T0, bfu* __restrict__ T1,
    bfu* __restrict__ T2, bfu* __restrict__ T3) {
  __shared__ bfu tile[64][65];
  const float* W; bfu* T;
  switch (blockIdx.z) {
    case 0:  W = W0; T = T0; break;
    case 1:  W = W1; T = T1; break;
    case 2:  W = W2; T = T2; break;
    default: W = W3; T = T3; break;
  }
  const int k0 = blockIdx.y * 64, n0 = blockIdx.x * 64;
  const int c = threadIdx.x & 63, r4 = threadIdx.x >> 6;
#pragma unroll
  for (int i = 0; i < 16; i++) {
    int row = r4 + i * 4;  // k-local
    tile[row][c] = f2bf(W[(size_t)(k0 + row) * 1024 + n0 + c]);
  }
  __syncthreads();
#pragma unroll
  for (int i = 0; i < 16; i++) {
    int row = r4 + i * 4;  // n-local
    T[(size_t)(n0 + row) * 1024 + k0 + c] = tile[c][row];
  }
}

// ---------------- GEMM core (m97 structure: 128x128 tile, BK=32) ----------------
// C[M,N] = A[M,K] * Bt[N,K]^T, A/Bt bf16 row-major. 256 threads = 4 waves (2x2).

DEVI void gemm128_core(const bfu* __restrict__ A, const bfu* __restrict__ Bt,
                       int K, int m0, int n0, bfu* As, bfu* Bs, int tid,
                       f32x4 acc[4][4]) {
  const int lane = tid & 63, wave = tid >> 6;
  const int wr = wave >> 1, wc = wave & 1;
  const int fr = lane & 15, fq = lane >> 4;
  const int r_a = tid >> 2;          // 0..63 staging row
  const int koff = (tid & 3) * 8;    // staging k offset (bf16 units)
  for (int k0 = 0; k0 < K; k0 += 32) {
    __syncthreads();
    gld_lds16(A  + (size_t)(m0 +      r_a) * K + k0 + koff, As        + tid * 8);
    gld_lds16(A  + (size_t)(m0 + 64 + r_a) * K + k0 + koff, As + 2048 + tid * 8);
    gld_lds16(Bt + (size_t)(n0 +      r_a) * K + k0 + koff, Bs        + tid * 8);
    gld_lds16(Bt + (size_t)(n0 + 64 + r_a) * K + k0 + koff, Bs + 2048 + tid * 8);
    __syncthreads();
    bf16x8 af[4], bfv[4];
#pragma unroll
    for (int m = 0; m < 4; m++)
      af[m] = *(const bf16x8*)&As[(wr * 64 + m * 16 + fr) * 32 + fq * 8];
#pragma unroll
    for (int n = 0; n < 4; n++)
      bfv[n] = *(const bf16x8*)&Bs[(wc * 64 + n * 16 + fr) * 32 + fq * 8];
#pragma unroll
    for (int m = 0; m < 4; m++)
#pragma unroll
      for (int n = 0; n < 4; n++)
        acc[m][n] = __builtin_amdgcn_mfma_f32_16x16x32_bf16(af[m], bfv[n],
                                                            acc[m][n], 0, 0, 0);
  }
}

// QKV projection: z=0 -> Q, z=1 -> K (layout [h32][t2048][d64]),
//                 z=2 -> V transposed ([h32][d64][t2048])
__global__ __launch_bounds__(256) void gemm_qkv(
    const bfu* __restrict__ A, const bfu* __restrict__ Wqt,
    const bfu* __restrict__ Wkt, const bfu* __restrict__ Wvt,
    bfu* __restrict__ Qb, bfu* __restrict__ Kb, bfu* __restrict__ Vb) {
  __shared__ __align__(16) bfu As[128 * 32];
  __shared__ __align__(16) bfu Bs[128 * 32];
  const bfu* Bt; bfu* out; int epi;
  if (blockIdx.z == 0)      { Bt = Wqt; out = Qb; epi = 0; }
  else if (blockIdx.z == 1) { Bt = Wkt; out = Kb; epi = 0; }
  else                      { Bt = Wvt; out = Vb; epi = 1; }
  const int m0 = blockIdx.y * 128, n0 = blockIdx.x * 128;
  const int tid = threadIdx.x, lane = tid & 63, wave = tid >> 6;
  const int wr = wave >> 1, wc = wave & 1, fr = lane & 15, fq = lane >> 4;
  f32x4 acc[4][4] = {};
  gemm128_core(A, Bt, 1024, m0, n0, As, Bs, tid, acc);
#pragma unroll
  for (int m = 0; m < 4; m++)
#pragma unroll
    for (int n = 0; n < 4; n++) {
      int r = m0 + wr * 64 + m * 16 + fq * 4;  // global row (b*2048+t), +i
      int c = n0 + wc * 64 + n * 16 + fr;      // global col (h*64+d)
      int b = r >> 11, t = r & 2047, h = c >> 6, d = c & 63;
      if (epi == 0) {
        size_t base = ((size_t)(b * 16 + h) * 2048 + t) * 64 + d;
#pragma unroll
        for (int i = 0; i < 4; i++) out[base + (size_t)i * 64] = f2bf(acc[m][n][i]);
      } else {
        size_t base = ((size_t)(b * 16 + h) * 64 + d) * 2048 + t;
        ushort4 p;
        p.x = f2bf(acc[m][n][0]); p.y = f2bf(acc[m][n][1]);
        p.z = f2bf(acc[m][n][2]); p.w = f2bf(acc[m][n][3]);
        *(ushort4*)&out[base] = p;  // 4 consecutive t -> contiguous
      }
    }
}

// output projection: out[4096][1024] fp32 = Ab @ Wpt^T + bias
__global__ __launch_bounds__(256) void gemm_proj(
    const bfu* __restrict__ A, const bfu* __restrict__ Bt,
    const float* __restrict__ bias, float* __restrict__ out) {
  __shared__ __align__(16) bfu As[128 * 32];
  __shared__ __align__(16) bfu Bs[128 * 32];
  const int m0 = blockIdx.y * 128, n0 = blockIdx.x * 128;
  const int tid = threadIdx.x, lane = tid & 63, wave = tid >> 6;
  const int wr = wave >> 1, wc = wave & 1, fr = lane & 15, fq = lane >> 4;
  f32x4 acc[4][4] = {};
  gemm128_core(A, Bt, 1024, m0, n0, As, Bs, tid, acc);
#pragma unroll
  for (int m = 0; m < 4; m++)
#pragma unroll
    for (int n = 0; n < 4; n++) {
      int r = m0 + wr * 64 + m * 16 + fq * 4;
      int c = n0 + wc * 64 + n * 16 + fr;
      float bv = bias[c];
#pragma unroll
      for (int i = 0; i < 4; i++)
        out[(size_t)(r + i) * 1024 + c] = acc[m][n][i] + bv;
    }
}

// ---------------- flash attention (causal), v2 ----------------
// 1024 WGs: one per (head-instance, q-block of 64 rows), largest qb first,
// XCD-swizzled so each head's K/V (512 KB) stays in one XCD's L2.
// K/V tiles double-buffered in LDS via global_load_lds (stage-early, one
// barrier per tile). XOR-swizzled layout (linear LDS dest + inverse-permuted
// global source; same involution on the read).

__global__ __launch_bounds__(256) void attn_fwd(
    const bfu* __restrict__ Q, const bfu* __restrict__ K,
    const bfu* __restrict__ Vt, bfu* __restrict__ Ob) {
  __shared__ __align__(16) bfu Ks[2][64 * 64];   // 8 KB each buf
  __shared__ __align__(16) bfu Vs[2][64 * 64];
  __shared__ __align__(16) bfu plds[4][16][72];  // per-wave P tile
  const int bid = blockIdx.x;
  const int xcd = bid & 7, idx = bid >> 3;       // 0..127
  const int hb = (idx & 3) * 8 + xcd;            // head instance 0..31 (= b*16+h)
  const int qb = 31 - (idx >> 2);                // descending: big blocks first
  const int tid = threadIdx.x, wave = tid >> 6, lane = tid & 63;
  const int fr = lane & 15, fq = lane >> 4;
  const bfu* Qh = Q  + (size_t)hb * 2048 * 64;
  const bfu* Kh = K  + (size_t)hb * 2048 * 64;
  const bfu* Vh = Vt + (size_t)hb * 64 * 2048;
  const int b = hb >> 4, h = hb & 15;
  const int qrow = qb * 64 + wave * 16;          // this wave's 16 q rows

  // staging geometry: 512 x 16B slots per tile; thread does slots tid, 256+tid.
  // linear slot s -> row = s>>3, col-group slot cg = s&7; content is global
  // col-group c = cg ^ (row&7)  (XOR involution).
  const int r0 = tid >> 3, r1 = (256 + tid) >> 3;
  const int c0 = (tid & 7) ^ (r0 & 7), c1 = (tid & 7) ^ (r1 & 7);

#define STAGE(bufi, kbase)                                                   \
  do {                                                                       \
    gld_lds16(Kh + (size_t)((kbase) + r0) * 64 + c0 * 8, &Ks[bufi][tid * 8]);        \
    gld_lds16(Kh + (size_t)((kbase) + r1) * 64 + c1 * 8, &Ks[bufi][(256 + tid) * 8]);\
    gld_lds16(Vh + (size_t)r0 * 2048 + (kbase) + c0 * 8, &Vs[bufi][tid * 8]);        \
    gld_lds16(Vh + (size_t)r1 * 2048 + (kbase) + c1 * 8, &Vs[bufi][(256 + tid) * 8]);\
  } while (0)

  bf16x8 qf[2];
  qf[0] = *(const bf16x8*)&Qh[(size_t)(qrow + fr) * 64 + fq * 8];
  qf[1] = *(const bf16x8*)&Qh[(size_t)(qrow + fr) * 64 + 32 + fq * 8];
  float mrow[4], lrow[4];
  f32x4 o[4] = {};
#pragma unroll
  for (int i = 0; i < 4; i++) { mrow[i] = -1e30f; lrow[i] = 0.f; }

  STAGE(0, 0);
  __syncthreads();

  const float sc2 = 0.125f * 1.44269504f;  // Dh^-0.5 * log2(e)  (exp2 domain)
  for (int kb = 0; kb <= qb; kb++) {
    const int cur = kb & 1;
    if (kb < qb) STAGE(cur ^ 1, (kb + 1) * 64);   // issue next tile early
    const int kbase = kb * 64;
    // S = Q K^T  (rows = q (fq*4+i), cols = k (fr)); K frags from swizzled LDS
    f32x4 s[4] = {};
#pragma unroll
    for (int kt = 0; kt < 4; kt++)
#pragma unroll
      for (int kk = 0; kk < 2; kk++) {
        bf16x8 kf = *(const bf16x8*)&Ks[cur][((kt * 16 + fr) * 8 +
                                             ((kk * 4 + fq) ^ (fr & 7))) * 8];
        s[kt] = __builtin_amdgcn_mfma_f32_16x16x32_bf16(qf[kk], kf, s[kt], 0, 0, 0);
      }
    if (kb == qb) {  // diagonal block: scale + causal mask
#pragma unroll
      for (int kt = 0; kt < 4; kt++)
#pragma unroll
        for (int i = 0; i < 4; i++) {
          int tc = kbase + kt * 16 + fr;
          int tq = qrow + fq * 4 + i;
          s[kt][i] = (tc <= tq) ? s[kt][i] * sc2 : -1e30f;
        }
    } else {
#pragma unroll
      for (int kt = 0; kt < 4; kt++) s[kt] *= sc2;
    }
    // online softmax (exp2 domain), wave-parallel over the 16 col-lanes
    float mnew[4], al[4], rs[4];
#pragma unroll
    for (int i = 0; i < 4; i++) {
      float v = fmaxf(fmaxf(s[0][i], s[1][i]), fmaxf(s[2][i], s[3][i]));
      v = fmaxf(v, __shfl_xor(v, 1));
      v = fmaxf(v, __shfl_xor(v, 2));
      v = fmaxf(v, __shfl_xor(v, 4));
      v = fmaxf(v, __shfl_xor(v, 8));
      mnew[i] = fmaxf(mrow[i], v);
      rs[i] = 0.f;
    }
#pragma unroll
    for (int kt = 0; kt < 4; kt++)
#pragma unroll
      for (int i = 0; i < 4; i++) {
        float p = __builtin_amdgcn_exp2f(s[kt][i] - mnew[i]);
        s[kt][i] = p;
        rs[i] += p;
      }
#pragma unroll
    for (int i = 0; i < 4; i++) {
      rs[i] += __shfl_xor(rs[i], 1);
      rs[i] += __shfl_xor(rs[i], 2);
      rs[i] += __shfl_xor(rs[i], 4);
      rs[i] += __shfl_xor(rs[i], 8);
      al[i] = __builtin_amdgcn_exp2f(mrow[i] - mnew[i]);
      lrow[i] = lrow[i] * al[i] + rs[i];
      mrow[i] = mnew[i];
    }
#pragma unroll
    for (int dt = 0; dt < 4; dt++) {
      o[dt][0] *= al[0]; o[dt][1] *= al[1];
      o[dt][2] *= al[2]; o[dt][3] *= al[3];
    }
    // P (acc layout) -> LDS -> A-fragment layout
#pragma unroll
    for (int kt = 0; kt < 4; kt++)
#pragma unroll
      for (int i = 0; i < 4; i++)
        plds[wave][fq * 4 + i][kt * 16 + fr] = f2bf(s[kt][i]);
    bf16x8 pa0 = *(const bf16x8*)&plds[wave][fr][fq * 8];
    bf16x8 pa1 = *(const bf16x8*)&plds[wave][fr][32 + fq * 8];
    // O += P V   (V frags from swizzled LDS; V-tile rows = d, cols = t)
#pragma unroll
    for (int dt = 0; dt < 4; dt++) {
      bf16x8 vf0 = *(const bf16x8*)&Vs[cur][((dt * 16 + fr) * 8 +
                                            ((0 + fq) ^ (fr & 7))) * 8];
      o[dt] = __builtin_amdgcn_mfma_f32_16x16x32_bf16(pa0, vf0, o[dt], 0, 0, 0);
      bf16x8 vf1 = *(const bf16x8*)&Vs[cur][((dt * 16 + fr) * 8 +
                                            ((4 + fq) ^ (fr & 7))) * 8];
      o[dt] = __builtin_amdgcn_mfma_f32_16x16x32_bf16(pa1, vf1, o[dt], 0, 0, 0);
    }
    __syncthreads();  // drains staged loads (vmcnt 0) + guards buffer reuse
  }
#undef STAGE

  // epilogue: Ob[b*2048+t][h*64+d]
#pragma unroll
  for (int dt = 0; dt < 4; dt++)
#pragma unroll
    for (int i = 0; i < 4; i++) {
      int t = qrow + fq * 4 + i;
      float val = o[dt][i] / lrow[i];
      Ob[(size_t)(b * 2048 + t) * 1024 + h * 64 + dt * 16 + fr] = f2bf(val);
    }
}

// ---------------- launch ----------------

extern "C" void kernel_launch(void* const* d_in, const int* in_sizes, int n_in,
                              void* d_out, int out_size, void* d_ws, size_t ws_size,
                              hipStream_t stream) {
  const float* x  = (const float*)d_in[0];
  const float* Wk = (const float*)d_in[1];  // note dict order: Wk before Wq!
  const float* Wq = (const float*)d_in[2];
  const float* Wv = (const float*)d_in[3];
  const float* Wp = (const float*)d_in[4];
  const float* bp = (const float*)d_in[5];
  char* ws = (char*)d_ws;
  bfu* xb  = (bfu*)(ws);
  bfu* Wqt = (bfu*)(ws + ( 8u << 20));
  bfu* Wkt = (bfu*)(ws + (10u << 20));
  bfu* Wvt = (bfu*)(ws + (12u << 20));
  bfu* Wpt = (bfu*)(ws + (14u << 20));
  bfu* Qb  = (bfu*)(ws + (16u << 20));
  bfu* Kb  = (bfu*)(ws + (24u << 20));
  bfu* Vb  = (bfu*)(ws + (32u << 20));
  bfu* Ab  = (bfu*)(ws + (40u << 20));
  float* out = (float*)d_out;

  conv_x<<<1024, 256, 0, stream>>>(x, xb);
  conv_w<<<dim3(16, 16, 4), 256, 0, stream>>>(Wq, Wk, Wv, Wp, Wqt, Wkt, Wvt, Wpt);
  gemm_qkv<<<dim3(8, 32, 3), 256, 0, stream>>>(xb, Wqt, Wkt, Wvt, Qb, Kb, Vb);
  attn_fwd<<<1024, 256, 0, stream>>>(Qb, Kb, Vb, Ab);
  gemm_proj<<<dim3(8, 32), 256, 0, stream>>>(Ab, Wpt, bp, out);
}

// Round 3
// 142.709 us; speedup vs baseline: 1.6554x; 1.0607x over previous
//
#include <hip/hip_runtime.h>
#include <stdint.h>

// MultiHeadAttention fused pipeline for MI355X (gfx950).
// B=2, T=2048, C=1024, H=16, Dh=64. All inputs fp32; compute in bf16 MFMA.
//
// ws layout (48 MiB):
//   [ 0MB) xb   : x as bf16            [4096][1024]
//   [ 8MB) Wqt  : Wq^T bf16            [1024 n][1024 k]
//   [10MB) Wkt, [12MB) Wvt, [14MB) Wpt
//   [16MB) Qb   : [32 head][2048 t][64 d] bf16  (PRE-SCALED by 0.125*log2e)
//   [24MB) Kb   : same layout (unscaled)
//   [32MB) Vb   : TRANSPOSED [32 head][64 d][2048 t] bf16
//   [40MB) Ab   : attention out [4096 row=b*T+t][1024 col=h*64+d] bf16

typedef unsigned short bfu;                               // bf16 bits
typedef unsigned int u32;
typedef short bf16x8 __attribute__((ext_vector_type(8))); // 8 bf16 (4 VGPRs)
typedef float f32x4 __attribute__((ext_vector_type(4)));
typedef float f32x16 __attribute__((ext_vector_type(16)));

#define DEVI static __device__ __forceinline__

DEVI bfu f2bf(float f) {  // round-to-nearest-even fp32 -> bf16 bits
  union { float f; unsigned u; } a; a.f = f;
  unsigned u = a.u;
  u += 0x7fffu + ((u >> 16) & 1u);
  return (bfu)(u >> 16);
}

DEVI void gld_lds16(const void* g, void* l) {
  __builtin_amdgcn_global_load_lds(
      (const __attribute__((address_space(1))) void*)g,
      (__attribute__((address_space(3))) void*)l, 16, 0, 0);
}

// ---------------- prep kernels ----------------

__global__ __launch_bounds__(256) void conv_x(const float* __restrict__ x,
                                              bfu* __restrict__ xb) {
  const int n4 = (4096 * 1024) / 4;
  for (int i = blockIdx.x * 256 + threadIdx.x; i < n4; i += gridDim.x * 256) {
    float4 v = ((const float4*)x)[i];
    ushort4 p;
    p.x = f2bf(v.x); p.y = f2bf(v.y); p.z = f2bf(v.z); p.w = f2bf(v.w);
    ((ushort4*)xb)[i] = p;
  }
}

// convert + transpose a 1024x1024 fp32 [k][n] -> bf16 [n][k]
__global__ __launch_bounds__(256) void conv_w(
    const float* __restrict__ W0, const float* __restrict__ W1,
    const float* __restrict__ W2, const float* __restrict__ W3,
    bfu* __restrict__ T0, bfu* __restrict__ T1,
    bfu* __restrict__ T2, bfu* __restrict__ T3) {
  __shared__ bfu tile[64][65];
  const float* W; bfu* T;
  switch (blockIdx.z) {
    case 0:  W = W0; T = T0; break;
    case 1:  W = W1; T = T1; break;
    case 2:  W = W2; T = T2; break;
    default: W = W3; T = T3; break;
  }
  const int k0 = blockIdx.y * 64, n0 = blockIdx.x * 64;
  const int c = threadIdx.x & 63, r4 = threadIdx.x >> 6;
#pragma unroll
  for (int i = 0; i < 16; i++) {
    int row = r4 + i * 4;  // k-local
    tile[row][c] = f2bf(W[(size_t)(k0 + row) * 1024 + n0 + c]);
  }
  __syncthreads();
#pragma unroll
  for (int i = 0; i < 16; i++) {
    int row = r4 + i * 4;  // n-local
    T[(size_t)(n0 + row) * 1024 + k0 + c] = tile[c][row];
  }
}

// ---------------- GEMM core (m97 structure: 128x128 tile, BK=32) ----------------

DEVI void gemm128_core(const bfu* __restrict__ A, const bfu* __restrict__ Bt,
                       int K, int m0, int n0, bfu* As, bfu* Bs, int tid,
                       f32x4 acc[4][4]) {
  const int lane = tid & 63, wave = tid >> 6;
  const int wr = wave >> 1, wc = wave & 1;
  const int fr = lane & 15, fq = lane >> 4;
  const int r_a = tid >> 2;          // 0..63 staging row
  const int koff = (tid & 3) * 8;    // staging k offset (bf16 units)
  for (int k0 = 0; k0 < K; k0 += 32) {
    __syncthreads();
    gld_lds16(A  + (size_t)(m0 +      r_a) * K + k0 + koff, As        + tid * 8);
    gld_lds16(A  + (size_t)(m0 + 64 + r_a) * K + k0 + koff, As + 2048 + tid * 8);
    gld_lds16(Bt + (size_t)(n0 +      r_a) * K + k0 + koff, Bs        + tid * 8);
    gld_lds16(Bt + (size_t)(n0 + 64 + r_a) * K + k0 + koff, Bs + 2048 + tid * 8);
    __syncthreads();
    bf16x8 af[4], bfv[4];
#pragma unroll
    for (int m = 0; m < 4; m++)
      af[m] = *(const bf16x8*)&As[(wr * 64 + m * 16 + fr) * 32 + fq * 8];
#pragma unroll
    for (int n = 0; n < 4; n++)
      bfv[n] = *(const bf16x8*)&Bs[(wc * 64 + n * 16 + fr) * 32 + fq * 8];
#pragma unroll
    for (int m = 0; m < 4; m++)
#pragma unroll
      for (int n = 0; n < 4; n++)
        acc[m][n] = __builtin_amdgcn_mfma_f32_16x16x32_bf16(af[m], bfv[n],
                                                            acc[m][n], 0, 0, 0);
  }
}

// QKV projection: z=0 -> Q (pre-scaled), z=1 -> K, z=2 -> V transposed
__global__ __launch_bounds__(256) void gemm_qkv(
    const bfu* __restrict__ A, const bfu* __restrict__ Wqt,
    const bfu* __restrict__ Wkt, const bfu* __restrict__ Wvt,
    bfu* __restrict__ Qb, bfu* __restrict__ Kb, bfu* __restrict__ Vb) {
  __shared__ __align__(16) bfu As[128 * 32];
  __shared__ __align__(16) bfu Bs[128 * 32];
  const bfu* Bt; bfu* out; int epi;
  if (blockIdx.z == 0)      { Bt = Wqt; out = Qb; epi = 0; }
  else if (blockIdx.z == 1) { Bt = Wkt; out = Kb; epi = 0; }
  else                      { Bt = Wvt; out = Vb; epi = 1; }
  const float qs = (blockIdx.z == 0) ? 0.1803368801f : 1.0f;  // 0.125*log2e
  const int m0 = blockIdx.y * 128, n0 = blockIdx.x * 128;
  const int tid = threadIdx.x, lane = tid & 63, wave = tid >> 6;
  const int wr = wave >> 1, wc = wave & 1, fr = lane & 15, fq = lane >> 4;
  f32x4 acc[4][4] = {};
  gemm128_core(A, Bt, 1024, m0, n0, As, Bs, tid, acc);
#pragma unroll
  for (int m = 0; m < 4; m++)
#pragma unroll
    for (int n = 0; n < 4; n++) {
      int r = m0 + wr * 64 + m * 16 + fq * 4;  // global row (b*2048+t), +i
      int c = n0 + wc * 64 + n * 16 + fr;      // global col (h*64+d)
      int b = r >> 11, t = r & 2047, h = c >> 6, d = c & 63;
      if (epi == 0) {
        size_t base = ((size_t)(b * 16 + h) * 2048 + t) * 64 + d;
#pragma unroll
        for (int i = 0; i < 4; i++)
          out[base + (size_t)i * 64] = f2bf(acc[m][n][i] * qs);
      } else {
        size_t base = ((size_t)(b * 16 + h) * 64 + d) * 2048 + t;
        ushort4 p;
        p.x = f2bf(acc[m][n][0]); p.y = f2bf(acc[m][n][1]);
        p.z = f2bf(acc[m][n][2]); p.w = f2bf(acc[m][n][3]);
        *(ushort4*)&out[base] = p;  // 4 consecutive t -> contiguous
      }
    }
}

// output projection: out[4096][1024] fp32 = Ab @ Wpt^T + bias
__global__ __launch_bounds__(256) void gemm_proj(
    const bfu* __restrict__ A, const bfu* __restrict__ Bt,
    const float* __restrict__ bias, float* __restrict__ out) {
  __shared__ __align__(16) bfu As[128 * 32];
  __shared__ __align__(16) bfu Bs[128 * 32];
  const int m0 = blockIdx.y * 128, n0 = blockIdx.x * 128;
  const int tid = threadIdx.x, lane = tid & 63, wave = tid >> 6;
  const int wr = wave >> 1, wc = wave & 1, fr = lane & 15, fq = lane >> 4;
  f32x4 acc[4][4] = {};
  gemm128_core(A, Bt, 1024, m0, n0, As, Bs, tid, acc);
#pragma unroll
  for (int m = 0; m < 4; m++)
#pragma unroll
    for (int n = 0; n < 4; n++) {
      int r = m0 + wr * 64 + m * 16 + fq * 4;
      int c = n0 + wc * 64 + n * 16 + fr;
      float bv = bias[c];
#pragma unroll
      for (int i = 0; i < 4; i++)
        out[(size_t)(r + i) * 1024 + c] = acc[m][n][i] + bv;
    }
}

// ---------------- flash attention (causal), v3: 32x32 swapped-operand ----------------
// 512 WGs: (head-instance, q-block of 128 rows). 4 waves x 32 q-rows, KVBLK=64.
// S^T = mfma(K, Q): lane holds P half-row for q=lane&31 -> in-register softmax.
// P->A-frag via cvt_pk_bf16 + permlane32_swap (T12). l via MFMA-ones (acc layout).
// Defer-max rescale (T13, THR=8). K/V dbuf LDS, XOR-swizzled (proven r2 scheme).

__global__ __launch_bounds__(256) void attn_fwd(
    const bfu* __restrict__ Q, const bfu* __restrict__ K,
    const bfu* __restrict__ Vt, bfu* __restrict__ Ob) {
  __shared__ __align__(16) bfu Ks[2][64 * 64];   // 8 KB each buf
  __shared__ __align__(16) bfu Vs[2][64 * 64];
  const int bid = blockIdx.x;
  const int xcd = bid & 7, idx = bid >> 3;       // idx 0..63
  const int hb = xcd * 4 + (idx & 3);            // head instance (= b*16+h)
  const int rank = idx >> 2;                     // 0..15
  const int qb = (rank < 8) ? (15 - rank) : (rank - 8);  // balanced pairing
  const int tid = threadIdx.x, wave = tid >> 6, lane = tid & 63;
  const int q31 = lane & 31, hi = lane >> 5;
  const bfu* Qh = Q  + (size_t)hb * 2048 * 64;
  const bfu* Kh = K  + (size_t)hb * 2048 * 64;
  const bfu* Vh = Vt + (size_t)hb * 64 * 2048;
  const int b = hb >> 4, h = hb & 15;
  const int q0w = qb * 128 + wave * 32;          // this wave's 32 q rows
  const int kbmax = 2 * qb + 1;
  const int qg = q0w + q31;

  // staging: 512 x 16B slots per tile; slot s -> row s>>3, slot-idx s&7 holds
  // global col-group (s&7) ^ (row&7) (XOR involution, proven in r2).
  const int r0 = tid >> 3, r1 = (256 + tid) >> 3;
  const int c0 = (tid & 7) ^ (r0 & 7), c1 = (tid & 7) ^ (r1 & 7);
#define STAGE(bufi, kbase)                                                            \
  do {                                                                                \
    gld_lds16(Kh + (size_t)((kbase) + r0) * 64 + c0 * 8, &Ks[bufi][tid * 8]);         \
    gld_lds16(Kh + (size_t)((kbase) + r1) * 64 + c1 * 8, &Ks[bufi][(256 + tid) * 8]); \
    gld_lds16(Vh + (size_t)r0 * 2048 + (kbase) + c0 * 8, &Vs[bufi][tid * 8]);         \
    gld_lds16(Vh + (size_t)r1 * 2048 + (kbase) + c1 * 8, &Vs[bufi][(256 + tid) * 8]); \
  } while (0)

  // Q as B-frags (4 d-chunks): B[d=8*hi+j][q=lane&31]
  bf16x8 qv[4];
#pragma unroll
  for (int c = 0; c < 4; c++)
    qv[c] = *(const bf16x8*)&Qh[(size_t)(q0w + q31) * 64 + c * 16 + hi * 8];

  bf16x8 onesv;
#pragma unroll
  for (int j = 0; j < 8; j++) onesv[j] = (short)0x3F80;  // bf16 1.0

  f32x16 o0 = {}, o1 = {}, lac = {};
  float m = -1e30f;

  STAGE(0, 0);
  __syncthreads();

  for (int kb = 0; kb <= kbmax; kb++) {
    const int cur = kb & 1;
    if (kb < kbmax) STAGE(cur ^ 1, (kb + 1) * 64);   // issue next tile early
    const int kbase = kb * 64;
    if (kbase <= q0w + 31) {                         // wave has unmasked work
      const bfu* KsC = Ks[cur];
      const bfu* VsC = Vs[cur];
      // S^T = K . Q^T : rows k (reg map), cols q (lane&31)
      f32x16 s0 = {}, s1 = {};
#pragma unroll
      for (int c = 0; c < 4; c++) {
        const int g = 2 * c + hi;
        bf16x8 kf0 = *(const bf16x8*)&KsC[(q31 * 8 + (g ^ (q31 & 7))) * 8];
        bf16x8 kf1 = *(const bf16x8*)&KsC[((32 + q31) * 8 + (g ^ (q31 & 7))) * 8];
        s0 = __builtin_amdgcn_mfma_f32_32x32x16_bf16(kf0, qv[c], s0, 0, 0, 0);
        s1 = __builtin_amdgcn_mfma_f32_32x32x16_bf16(kf1, qv[c], s1, 0, 0, 0);
      }
      if (kbase + 63 > q0w) {  // tile crosses diagonal: causal mask
#pragma unroll
        for (int r = 0; r < 16; r++) {
          int krow = (r & 3) + 8 * (r >> 2) + 4 * hi;
          if (kbase + krow > qg)      s0[r] = -1e30f;
          if (kbase + 32 + krow > qg) s1[r] = -1e30f;
        }
      }
      // row max: 31 local fmax + one cross-half swap
      float pm = s0[0];
#pragma unroll
      for (int r = 1; r < 16; r++) pm = fmaxf(pm, s0[r]);
#pragma unroll
      for (int r = 0; r < 16; r++) pm = fmaxf(pm, s1[r]);
      pm = fmaxf(pm, __shfl_xor(pm, 32));
      // defer-max (T13): rescale only when max grows > 8 (exp2 domain)
      if (!__all(pm <= m + 8.0f)) {
        float mn = fmaxf(m, pm);
        float al = __builtin_amdgcn_exp2f(m - mn);
        m = mn;
#pragma unroll
        for (int r = 0; r < 16; r++) {
          float alq = __shfl(al, (r & 3) + 8 * (r >> 2) + 4 * hi);
          o0[r] *= alq; o1[r] *= alq; lac[r] *= alq;
        }
      }
      // p = exp2(s - m); pack pairs to bf16 words (16 cvt_pk)
      u32 W0[8], W1[8];
#pragma unroll
      for (int w = 0; w < 8; w++) {
        float a0 = __builtin_amdgcn_exp2f(s0[2 * w] - m);
        float a1 = __builtin_amdgcn_exp2f(s0[2 * w + 1] - m);
        asm("v_cvt_pk_bf16_f32 %0, %1, %2" : "=v"(W0[w]) : "v"(a0), "v"(a1));
        float b0 = __builtin_amdgcn_exp2f(s1[2 * w] - m);
        float b1 = __builtin_amdgcn_exp2f(s1[2 * w + 1] - m);
        asm("v_cvt_pk_bf16_f32 %0, %1, %2" : "=v"(W1[w]) : "v"(b0), "v"(b1));
      }
      // PV + l, per 16-k chunk: A-frag via 2 permlane32_swap per chunk (T12)
      __builtin_amdgcn_s_setprio(1);
#pragma unroll
      for (int c = 0; c < 4; c++) {
        const u32* Wsel = (c < 2) ? W0 : W1;
        const int w0 = 4 * (c & 1);
        u32 t0 = Wsel[w0],     t2 = Wsel[w0 + 2];
        u32 t1 = Wsel[w0 + 1], t3 = Wsel[w0 + 3];
        asm("v_permlane32_swap_b32 %0, %1" : "+v"(t0), "+v"(t2));
        asm("v_permlane32_swap_b32 %0, %1" : "+v"(t1), "+v"(t3));
        union { u32 u[4]; bf16x8 v; } pa;
        pa.u[0] = t0; pa.u[1] = t1; pa.u[2] = t2; pa.u[3] = t3;
        const int g = 2 * c + hi;
        bf16x8 vb0 = *(const bf16x8*)&VsC[(q31 * 8 + (g ^ (q31 & 7))) * 8];
        bf16x8 vb1 = *(const bf16x8*)&VsC[((32 + q31) * 8 + (g ^ (q31 & 7))) * 8];
        o0  = __builtin_amdgcn_mfma_f32_32x32x16_bf16(pa.v, vb0,   o0,  0, 0, 0);
        o1  = __builtin_amdgcn_mfma_f32_32x32x16_bf16(pa.v, vb1,   o1,  0, 0, 0);
        lac = __builtin_amdgcn_mfma_f32_32x32x16_bf16(pa.v, onesv, lac, 0, 0, 0);
      }
      __builtin_amdgcn_s_setprio(0);
    }
    __syncthreads();  // drains staged loads + guards buffer reuse
  }
#undef STAGE

  // epilogue: Ob[b*2048+t][h*64+d]; o layout: col d = lane&31 (+32), row q = reg map
#pragma unroll
  for (int r = 0; r < 16; r++) {
    int t = q0w + (r & 3) + 8 * (r >> 2) + 4 * hi;
    float inv = 1.0f / lac[r];
    size_t base = (size_t)(b * 2048 + t) * 1024 + h * 64;
    Ob[base + q31]      = f2bf(o0[r] * inv);
    Ob[base + 32 + q31] = f2bf(o1[r] * inv);
  }
}

// ---------------- launch ----------------

extern "C" void kernel_launch(void* const* d_in, const int* in_sizes, int n_in,
                              void* d_out, int out_size, void* d_ws, size_t ws_size,
                              hipStream_t stream) {
  const float* x  = (const float*)d_in[0];
  const float* Wk = (const float*)d_in[1];  // note dict order: Wk before Wq!
  const float* Wq = (const float*)d_in[2];
  const float* Wv = (const float*)d_in[3];
  const float* Wp = (const float*)d_in[4];
  const float* bp = (const float*)d_in[5];
  char* ws = (char*)d_ws;
  bfu* xb  = (bfu*)(ws);
  bfu* Wqt = (bfu*)(ws + ( 8u << 20));
  bfu* Wkt = (bfu*)(ws + (10u << 20));
  bfu* Wvt = (bfu*)(ws + (12u << 20));
  bfu* Wpt = (bfu*)(ws + (14u << 20));
  bfu* Qb  = (bfu*)(ws + (16u << 20));
  bfu* Kb  = (bfu*)(ws + (24u << 20));
  bfu* Vb  = (bfu*)(ws + (32u << 20));
  bfu* Ab  = (bfu*)(ws + (40u << 20));
  float* out = (float*)d_out;

  conv_x<<<1024, 256, 0, stream>>>(x, xb);
  conv_w<<<dim3(16, 16, 4), 256, 0, stream>>>(Wq, Wk, Wv, Wp, Wqt, Wkt, Wvt, Wpt);
  gemm_qkv<<<dim3(8, 32, 3), 256, 0, stream>>>(xb, Wqt, Wkt, Wvt, Qb, Kb, Vb);
  attn_fwd<<<512, 256, 0, stream>>>(Qb, Kb, Vb, Ab);
  gemm_proj<<<dim3(8, 32), 256, 0, stream>>>(Ab, Wpt, bp, out);
}